// Round 2
// baseline (190.875 us; speedup 1.0000x reference)
//
#include <hip/hip_runtime.h>
#include <stdint.h>

#define N_ROWS 8192
#define DIM 128
#define LDA 136        // LDS pitch in bf16 elems: 128+8 -> 272B rows (bank spread)
#define BM 128
#define JCHUNK 1024
#define NJT (JCHUNK / BM)
#define INV_T 14.2857142857142857f       // 1/0.07
#define K1 20.6099291555566280f          // log2(e)/0.07 ; t = c*K1 - K1 ; exp(l-m)=exp2(t)

typedef short bf16x8 __attribute__((ext_vector_type(8)));
typedef float f32x4 __attribute__((ext_vector_type(4)));

template <bool B> struct BoolC { static constexpr bool value = B; };

__device__ __forceinline__ unsigned int f2bf(float x) {
  union { float f; unsigned u; } c; c.f = x;
  return (c.u + 0x7FFFu + ((c.u >> 16) & 1u)) >> 16;  // RNE to bf16
}
__device__ __forceinline__ float bf2f(unsigned b) {
  union { unsigned u; float f; } c; c.u = b << 16;
  return c.f;
}

// Kernel 1: L2-normalize rows fp32 -> bf16 (ws); fused class-sum + class-count atomics.
__global__ __launch_bounds__(256) void normalize_kernel(
    const float* __restrict__ F, const int* __restrict__ L,
    unsigned short* __restrict__ Abf, float* __restrict__ csum,
    float* __restrict__ cntf) {
  const int wave = threadIdx.x >> 6, lane = threadIdx.x & 63;
  const int row = blockIdx.x * 4 + wave;
  float2 v = ((const float2*)(F + (size_t)row * DIM))[lane];
  float ss = v.x * v.x + v.y * v.y;
  #pragma unroll
  for (int m = 1; m < 64; m <<= 1) ss += __shfl_xor(ss, m, 64);
  float scale = rsqrtf(fmaxf(ss, 1e-24f));
  unsigned bx = f2bf(v.x * scale), by = f2bf(v.y * scale);
  ((unsigned*)Abf)[(size_t)row * (DIM / 2) + lane] = bx | (by << 16);
  const int lab = L[row];
  float fx = bf2f(bx), fy = bf2f(by);
  atomicAdd(&csum[lab * DIM + 2 * lane], fx);
  atomicAdd(&csum[lab * DIM + 2 * lane + 1], fy);
  if (lane == 0) atomicAdd(&cntf[lab], 1.0f);
}

// Kernel 2: C = A*A^T, epilogue accumulates only Z_i = sum_j exp2(K1*c - K1), diag excluded.
__global__ __launch_bounds__(256, 2) void scl_z_kernel(
    const unsigned short* __restrict__ Abf, float* __restrict__ Z) {
  __shared__ unsigned short sA[BM * LDA];
  __shared__ unsigned short sB[BM * LDA];

  const int tid = threadIdx.x;
  const int lane = tid & 63;
  const int wave = tid >> 6;
  const int wi = wave >> 1, wj = wave & 1;
  const int quad = lane >> 4, l15 = lane & 15;

  const int i0 = blockIdx.y * BM;
  const int j0 = blockIdx.x * JCHUNK;

  // stage A_I tile (128 x 128 bf16)
  #pragma unroll
  for (int k = 0; k < 8; ++k) {
    int idx = tid + k * 256;
    int r = idx >> 4, c = idx & 15;
    uint4 v = ((const uint4*)(Abf + (size_t)(i0 + r) * DIM))[c];
    *(uint4*)&sA[r * LDA + c * 8] = v;
  }

  float zacc[16];
  #pragma unroll
  for (int q = 0; q < 16; ++q) zacc[q] = 0.f;

  for (int jt = 0; jt < NJT; ++jt) {
    __syncthreads();
    const int jb = j0 + jt * BM;
    #pragma unroll
    for (int k = 0; k < 8; ++k) {
      int idx = tid + k * 256;
      int r = idx >> 4, c = idx & 15;
      uint4 v = ((const uint4*)(Abf + (size_t)(jb + r) * DIM))[c];
      *(uint4*)&sB[r * LDA + c * 8] = v;
    }
    __syncthreads();

    f32x4 acc[4][4];
    #pragma unroll
    for (int a = 0; a < 4; ++a)
      #pragma unroll
      for (int b = 0; b < 4; ++b)
        acc[a][b] = (f32x4){0.f, 0.f, 0.f, 0.f};

    #pragma unroll
    for (int ks = 0; ks < 4; ++ks) {
      bf16x8 af[4], bfr[4];
      #pragma unroll
      for (int ti = 0; ti < 4; ++ti)
        af[ti] = *(const bf16x8*)&sA[(wi * 64 + ti * 16 + l15) * LDA + ks * 32 + quad * 8];
      #pragma unroll
      for (int tj = 0; tj < 4; ++tj)
        bfr[tj] = *(const bf16x8*)&sB[(wj * 64 + tj * 16 + l15) * LDA + ks * 32 + quad * 8];
      #pragma unroll
      for (int ti = 0; ti < 4; ++ti)
        #pragma unroll
        for (int tj = 0; tj < 4; ++tj)
          acc[ti][tj] = __builtin_amdgcn_mfma_f32_16x16x32_bf16(af[ti], bfr[tj], acc[ti][tj], 0, 0, 0);
    }

    // epilogue: C/D layout col = lane&15, row = quad*4 + reg
    auto epi = [&](auto DIAG) {
      #pragma unroll
      for (int ti = 0; ti < 4; ++ti) {
        #pragma unroll
        for (int rg = 0; rg < 4; ++rg) {
          float z = 0.f;
          #pragma unroll
          for (int tj = 0; tj < 4; ++tj) {
            float c = acc[ti][tj][rg];
            float e = __builtin_amdgcn_exp2f(fmaf(c, K1, -K1));
            if constexpr (decltype(DIAG)::value) {
              int rloc = wi * 64 + ti * 16 + quad * 4 + rg;
              int cloc = wj * 64 + tj * 16 + l15;
              e = (rloc != cloc) ? e : 0.f;
            }
            z += e;
          }
          zacc[ti * 4 + rg] += z;
        }
      }
    };
    if (jb == i0) epi(BoolC<true>{}); else epi(BoolC<false>{});
  }

  // merging transpose-reduce over the 16 lanes of each quad: 15 shuffles total,
  // ends with lane l15 == q holding the full sum of array index q.
  float v[16];
  #pragma unroll
  for (int q = 0; q < 16; ++q) v[q] = zacc[q];
  #pragma unroll
  for (int m = 1; m < 16; m <<= 1) {
    #pragma unroll
    for (int q = 0; q < 16 / (2 * m); ++q) {
      float a = v[2 * q], b = v[2 * q + 1];
      bool hi = (l15 & m) != 0;
      float mine = hi ? b : a;
      float send = hi ? a : b;
      v[q] = mine + __shfl_xor(send, m, 64);
    }
  }
  // v[0] on lane (quad,l15) = row-total of local row (l15>>2)*16 + quad*4 + (l15&3)
  const int grow = i0 + wi * 64 + (l15 >> 2) * 16 + quad * 4 + (l15 & 3);
  atomicAdd(&Z[grow], v[0]);
}

// Kernel 3: per-row loss; grid-total via done-counter; last block writes out.
__global__ __launch_bounds__(256) void rowstats_kernel(
    const unsigned short* __restrict__ Abf, const int* __restrict__ L,
    const float* __restrict__ csum, const float* __restrict__ cntf,
    const float* __restrict__ Z, float* __restrict__ acc,
    unsigned int* __restrict__ done, float* __restrict__ out) {
  __shared__ float red[4];
  const int tid = threadIdx.x, lane = tid & 63, wave = tid >> 6;
  const int row = blockIdx.x * 4 + wave;
  const int lab = L[row];
  unsigned pk = ((const unsigned*)Abf)[(size_t)row * (DIM / 2) + lane];
  float x = bf2f(pk & 0xFFFFu), y = bf2f(pk >> 16);
  float2 cs = ((const float2*)(csum + lab * DIM))[lane];
  float pd = fmaf(x, cs.x, y * cs.y);     // dot(f_i, csum[lab]) partial
  float sd = fmaf(x, x, y * y);           // self-dot partial
  #pragma unroll
  for (int m = 1; m < 64; m <<= 1) {
    pd += __shfl_xor(pd, m, 64);
    sd += __shfl_xor(sd, m, 64);
  }
  if (lane == 0) {
    float Pi = cntf[lab] - 1.0f;
    float posd = pd - sd;                 // sum of positive sims, self excluded
    float mlp = INV_T * (posd / Pi - 1.0f) - logf(Z[row] + 1e-12f);
    red[wave] = mlp;
  }
  __syncthreads();
  if (tid == 0) {
    float s4 = red[0] + red[1] + red[2] + red[3];
    atomicAdd(acc, s4);
    __threadfence();
    unsigned old = atomicAdd(done, 1u);
    if (old == (unsigned)(N_ROWS / 4 - 1)) {
      float tot = atomicAdd(acc, 0.0f);   // atomic read: all adds visible
      out[0] = -tot / (float)N_ROWS;
    }
  }
}

extern "C" void kernel_launch(void* const* d_in, const int* in_sizes, int n_in,
                              void* d_out, int out_size, void* d_ws, size_t ws_size,
                              hipStream_t stream) {
  const float* F = (const float*)d_in[0];
  const int* L = (const int*)d_in[1];
  unsigned short* Abf = (unsigned short*)d_ws;                 // 8192*128 bf16 = 2 MB
  float* fws = (float*)((char*)d_ws + (size_t)N_ROWS * DIM * 2);
  float* Z = fws;                    // 8192
  float* csum = Z + N_ROWS;          // 100*128 = 12800
  float* cntf = csum + 100 * DIM;    // 100
  float* acc = cntf + 100;           // 1
  unsigned int* done = (unsigned int*)(acc + 1);               // 1
  float* out = (float*)d_out;

  size_t zero_bytes = (size_t)(N_ROWS + 100 * DIM + 100 + 1 + 1) * 4;
  hipMemsetAsync(Z, 0, zero_bytes, stream);

  normalize_kernel<<<N_ROWS / 4, 256, 0, stream>>>(F, L, Abf, csum, cntf);
  dim3 grid(N_ROWS / JCHUNK, N_ROWS / BM);  // (8, 64) = 512 blocks
  scl_z_kernel<<<grid, 256, 0, stream>>>(Abf, Z);
  rowstats_kernel<<<N_ROWS / 4, 256, 0, stream>>>(Abf, L, csum, cntf, Z, acc, done, out);
}

// Round 3
// 135.636 us; speedup vs baseline: 1.4073x; 1.4073x over previous
//
#include <hip/hip_runtime.h>
#include <stdint.h>

#define N_ROWS 8192
#define DIM 128
#define LDA 136        // LDS pitch in bf16 elems
#define BM 128
#define JCHUNK 1024
#define NJT (JCHUNK / BM)
#define NBLK 512       // scl_z grid size (8 x 64)
#define INV_T 14.2857142857142857f       // 1/0.07
#define K1 20.6099291555566280f          // log2(e)/0.07
#define SQK1 4.53981598960893f           // sqrt(K1); A' = f_norm * SQK1
#define LN2 0.69314718055994531f

typedef short bf16x8 __attribute__((ext_vector_type(8)));
typedef float f32x4 __attribute__((ext_vector_type(4)));

template <bool B> struct BoolC { static constexpr bool value = B; };

__device__ __forceinline__ unsigned int f2bf(float x) {
  union { float f; unsigned u; } c; c.f = x;
  return (c.u + 0x7FFFu + ((c.u >> 16) & 1u)) >> 16;  // RNE to bf16
}
__device__ __forceinline__ float bf2f(unsigned b) {
  union { unsigned u; float f; } c; c.u = b << 16;
  return c.f;
}

// Kernel 1: L2-normalize + scale by sqrt(K1), fp32 -> bf16 (ws); class-sum atomics.
__global__ __launch_bounds__(256) void normalize_kernel(
    const float* __restrict__ F, const int* __restrict__ L,
    unsigned short* __restrict__ Abf, float* __restrict__ csum,
    float* __restrict__ cntf) {
  const int wave = threadIdx.x >> 6, lane = threadIdx.x & 63;
  const int row = blockIdx.x * 4 + wave;
  float2 v = ((const float2*)(F + (size_t)row * DIM))[lane];
  float ss = v.x * v.x + v.y * v.y;
  #pragma unroll
  for (int m = 1; m < 64; m <<= 1) ss += __shfl_xor(ss, m, 64);
  float scale = rsqrtf(fmaxf(ss, 1e-24f)) * SQK1;
  unsigned bx = f2bf(v.x * scale), by = f2bf(v.y * scale);
  ((unsigned*)Abf)[(size_t)row * (DIM / 2) + lane] = bx | (by << 16);
  const int lab = L[row];
  atomicAdd(&csum[lab * DIM + 2 * lane], bf2f(bx));
  atomicAdd(&csum[lab * DIM + 2 * lane + 1], bf2f(by));
  if (lane == 0) atomicAdd(&cntf[lab], 1.0f);
}

// Kernel 2: C' = A'*A'^T (= K1 * cos-sim). Z_i = sum_{j!=i} exp2(C'_ij).
// Winner block (done-counter) computes the final scalar loss.
__global__ __launch_bounds__(256, 2) void scl_z_kernel(
    const unsigned short* __restrict__ Abf, const float* __restrict__ csum,
    const float* __restrict__ cntf, float* __restrict__ Z,
    unsigned int* __restrict__ done, float* __restrict__ out) {
  __shared__ unsigned short sA[BM * LDA];
  __shared__ unsigned short sB[BM * LDA];

  const int tid = threadIdx.x;
  const int lane = tid & 63;
  const int wave = tid >> 6;
  const int wi = wave >> 1, wj = wave & 1;
  const int quad = lane >> 4, l15 = lane & 15;

  const int i0 = blockIdx.y * BM;
  const int j0 = blockIdx.x * JCHUNK;

  // stage A_I tile (128 x 128 bf16)
  #pragma unroll
  for (int k = 0; k < 8; ++k) {
    int idx = tid + k * 256;
    int r = idx >> 4, c = idx & 15;
    uint4 v = ((const uint4*)(Abf + (size_t)(i0 + r) * DIM))[c];
    *(uint4*)&sA[r * LDA + c * 8] = v;
  }
  __syncthreads();

  // hoist this wave's A fragments for the whole J-loop (16 x bf16x8 = 64 VGPRs)
  bf16x8 af[16];
  #pragma unroll
  for (int ks = 0; ks < 4; ++ks)
    #pragma unroll
    for (int ti = 0; ti < 4; ++ti)
      af[ks * 4 + ti] = *(const bf16x8*)&sA[(wi * 64 + ti * 16 + l15) * LDA + ks * 32 + quad * 8];

  float zacc[16];
  #pragma unroll
  for (int q = 0; q < 16; ++q) zacc[q] = 0.f;

  for (int jt = 0; jt < NJT; ++jt) {
    __syncthreads();                       // prior iter done reading sB
    const int jb = j0 + jt * BM;
    #pragma unroll
    for (int k = 0; k < 8; ++k) {
      int idx = tid + k * 256;
      int r = idx >> 4, c = idx & 15;
      uint4 v = ((const uint4*)(Abf + (size_t)(jb + r) * DIM))[c];
      *(uint4*)&sB[r * LDA + c * 8] = v;
    }
    __syncthreads();

    f32x4 acc[4][4];
    #pragma unroll
    for (int a = 0; a < 4; ++a)
      #pragma unroll
      for (int b = 0; b < 4; ++b)
        acc[a][b] = (f32x4){0.f, 0.f, 0.f, 0.f};

    #pragma unroll
    for (int ks = 0; ks < 4; ++ks) {
      bf16x8 bfr[4];
      #pragma unroll
      for (int tj = 0; tj < 4; ++tj)
        bfr[tj] = *(const bf16x8*)&sB[(wj * 64 + tj * 16 + l15) * LDA + ks * 32 + quad * 8];
      #pragma unroll
      for (int ti = 0; ti < 4; ++ti)
        #pragma unroll
        for (int tj = 0; tj < 4; ++tj)
          acc[ti][tj] = __builtin_amdgcn_mfma_f32_16x16x32_bf16(af[ks * 4 + ti], bfr[tj], acc[ti][tj], 0, 0, 0);
    }

    // epilogue: exp2 of the raw (pre-scaled) logits, accumulate Z only.
    auto epi = [&](auto DIAG) {
      #pragma unroll
      for (int ti = 0; ti < 4; ++ti) {
        #pragma unroll
        for (int rg = 0; rg < 4; ++rg) {
          float z = 0.f;
          #pragma unroll
          for (int tj = 0; tj < 4; ++tj) {
            float e = __builtin_amdgcn_exp2f(acc[ti][tj][rg]);
            if constexpr (decltype(DIAG)::value) {
              int rloc = wi * 64 + ti * 16 + quad * 4 + rg;
              int cloc = wj * 64 + tj * 16 + l15;
              e = (rloc != cloc) ? e : 0.f;
            }
            z += e;
          }
          zacc[ti * 4 + rg] += z;
        }
      }
    };
    if (jb == i0) epi(BoolC<true>{}); else epi(BoolC<false>{});
  }

  // merging transpose-reduce over each 16-lane group: 15 shuffles, one atomic/lane.
  float v[16];
  #pragma unroll
  for (int q = 0; q < 16; ++q) v[q] = zacc[q];
  #pragma unroll
  for (int m = 1; m < 16; m <<= 1) {
    #pragma unroll
    for (int q = 0; q < 16 / (2 * m); ++q) {
      float a = v[2 * q], b = v[2 * q + 1];
      bool hi = (l15 & m) != 0;
      float mine = hi ? b : a;
      float send = hi ? a : b;
      v[q] = mine + __shfl_xor(send, m, 64);
    }
  }
  const int grow = i0 + wi * 64 + (l15 >> 2) * 16 + quad * 4 + (l15 & 3);
  atomicAdd(&Z[grow], v[0]);

  // -------- winner-block finalize --------
  __shared__ int sWin;
  __shared__ float red[8];
  __syncthreads();                          // all Z atomics of this block retired
  if (tid == 0) {
    __threadfence();
    unsigned old = atomicAdd(done, 1u);
    sWin = (old == NBLK - 1) ? 1 : 0;
  }
  __syncthreads();
  if (!sWin) return;

  // last block: all Z complete & visible (512 fenced increments observed).
  float lsum = 0.f;
  for (int r = tid; r < N_ROWS; r += 256) {
    float z = atomicAdd(&Z[r], 0.0f);       // coherent read
    lsum += __log2f(z);
  }
  float cpart = 0.f;
  if (tid < 100) {
    const float4* cp = (const float4*)(csum + tid * DIM);
    float d = 0.f;
    #pragma unroll
    for (int k = 0; k < 32; ++k) {
      float4 q = cp[k];
      d += q.x * q.x + q.y * q.y + q.z * q.z + q.w * q.w;
    }
    float n = cntf[tid];
    // sum_{i in c} posd_i / P_i = (||csum_c||^2 - n*K1) / (K1*(n-1))   [cosine units]
    cpart = (d - n * K1) / (K1 * (n - 1.0f));
  }
  #pragma unroll
  for (int m = 1; m < 64; m <<= 1) {
    lsum += __shfl_xor(lsum, m, 64);
    cpart += __shfl_xor(cpart, m, 64);
  }
  if (lane == 0) { red[wave] = lsum; red[4 + wave] = cpart; }
  __syncthreads();
  if (tid == 0) {
    float logsum = red[0] + red[1] + red[2] + red[3];
    float csumt = red[4] + red[5] + red[6] + red[7];
    // sum_i mlp_i = INV_T * csumt - N*INV_T - sum_i ln(Z_i * 2^-K1)
    float total = INV_T * csumt - (float)N_ROWS * INV_T
                - LN2 * (logsum - (float)N_ROWS * K1);
    out[0] = -total / (float)N_ROWS;
  }
}

extern "C" void kernel_launch(void* const* d_in, const int* in_sizes, int n_in,
                              void* d_out, int out_size, void* d_ws, size_t ws_size,
                              hipStream_t stream) {
  const float* F = (const float*)d_in[0];
  const int* L = (const int*)d_in[1];
  unsigned short* Abf = (unsigned short*)d_ws;                 // 8192*128 bf16 = 2 MB
  float* fws = (float*)((char*)d_ws + (size_t)N_ROWS * DIM * 2);
  float* Z = fws;                          // 8192
  float* csum = Z + N_ROWS;                // 100*128
  float* cntf = csum + 100 * DIM;          // 100
  unsigned int* done = (unsigned int*)(cntf + 100);            // 1
  float* out = (float*)d_out;

  size_t zero_bytes = (size_t)(N_ROWS + 100 * DIM + 100 + 1) * 4;
  hipMemsetAsync(Z, 0, zero_bytes, stream);

  normalize_kernel<<<N_ROWS / 4, 256, 0, stream>>>(F, L, Abf, csum, cntf);
  dim3 grid(N_ROWS / JCHUNK, N_ROWS / BM);  // (8, 64) = 512 blocks
  scl_z_kernel<<<grid, 256, 0, stream>>>(Abf, csum, cntf, Z, done, out);
}